// Round 12
// baseline (1559.292 us; speedup 1.0000x reference)
//
#include <hip/hip_runtime.h>
#include <hip/hip_fp16.h>
#include <cstdint>
#include <cstddef>

#define B_   2048
#define T_   13
#define D0_  188
#define H_   256
#define G_   768   // 3*H
#define L_   8
#define DC_  512   // 2*H concat width
#define WFLD_ (8*48*64*8)   // halfs per (layer,dir) in fragment-packed W_hh = 196608

typedef _Float16 half8_ __attribute__((ext_vector_type(8)));
typedef float    f32x4_ __attribute__((ext_vector_type(4)));

__device__ __forceinline__ float sigmoidf_(float x){ return 1.f/(1.f + expf(-x)); }

// async global->LDS, 16B per lane; LDS dest = wave-uniform base + lane*16 (m104/m108)
__device__ __forceinline__ void gld_lds16(const __half* g, __half* l){
  __builtin_amdgcn_global_load_lds(
      (const __attribute__((address_space(1))) void*)g,
      (__attribute__((address_space(3))) void*)l, 16, 0, 0);
}

// ---------------- fallback: zero d_out (diagnostic path if ws_size is tiny) ----------------
__global__ __launch_bounds__(256) void k_zero(float* __restrict__ o, int n){
  int i = blockIdx.x*256 + threadIdx.x;
  if (i < n) o[i] = 0.f;
}

// ---------------- pack W_hh [16][G][H] fp32 -> MFMA B-fragment layout fp16 ----------------
__global__ __launch_bounds__(64) void k_pack_whh(const float* __restrict__ W,
                                                 __half* __restrict__ WF){
  int kk = blockIdx.x, c = blockIdx.y, ld = blockIdx.z;
  int lane = threadIdx.x, n = lane & 15, quad = lane >> 4;
  int col = c*16 + n;
  const float* src = W + ((size_t)ld*G_ + col)*H_ + kk*32 + quad*8;
  __half tmp[8];
#pragma unroll
  for (int j=0;j<8;j++) tmp[j] = __float2half(src[j]);
  *(uint4*)(WF + (size_t)ld*WFLD_ + (((size_t)kk*48 + c)*64 + lane)*8) = *(uint4*)tmp;
}

// ---------------- guarded fp32 -> 8 halfs ----------------
__device__ __forceinline__ void load8_(const float* s, int rem, __half* d){
  if (rem >= 8){
#pragma unroll
    for (int u=0;u<8;u++) d[u] = __float2half(s[u]);
  } else {
#pragma unroll
    for (int u=0;u<8;u++) d[u] = (u<rem) ? __float2half(s[u]) : __ushort_as_half((unsigned short)0);
  }
}

// ---------------- x fp32 [C][T][188] -> buf fp16 [C][T][512] cols 0..191 (zero-pad 188..191)
__global__ __launch_bounds__(256) void k_cvt_x(const float* __restrict__ x,
                                               __half* __restrict__ buf, int C){
  int idx = blockIdx.x*256 + threadIdx.x;         // C*T*24 items of 8 halfs
  if (idx >= C*T_*24) return;
  int seg = (idx % 24) * 8;                       // 0..184
  int bt  = idx / 24;
  __half tmp[8];
  load8_(x + (size_t)bt*D0_ + seg, D0_ - seg, tmp);
  *(uint4*)&buf[(size_t)bt*DC_ + seg] = *(uint4*)tmp;
}

// ---------------- gx GEMM: BM=128 BN=128 BK=64, 4 waves (64x64 quadrant each).
// A staged via global_load_lds w=16 into XOR-swizzled As[128][64] (DMA needs contiguous
// dest, so lane l SOURCES segment (l&7)^(l>>3); readers index seg=(sub*4+quad)^(ln&7)
// -> 2-way banks, free). B (fp32 weights) cvt-staged into padded Bs[128][72].
// MFMA k-order identical to R11 -> bitwise-identical results.
__global__ __launch_bounds__(256) void k_gx_mfma(
    const __half* __restrict__ A,    // [C][T][DC_] fp16 (layer0: x-f16 in cols 0..191)
    const float* __restrict__ Wi,    // [2][G][KinW] fp32
    const float* __restrict__ bihL,  // [2][G] fp32
    __half* __restrict__ gx,         // [2][T][C][G] fp16
    int C, int KinW, int Kpad)
{
  __shared__ __align__(16) __half As[128][64];   // 16 KB, swizzled
  __shared__ __align__(16) __half Bs[128][72];   // 18 KB, stride 144 B (16B-aligned rows)
  const int dir = blockIdx.z / T_, t = blockIdx.z % T_;
  const int b0 = blockIdx.x*128, g0 = blockIdx.y*128;
  const int tid = threadIdx.x;
  const int wave = tid>>6, lane = tid&63;
  const int quad = lane>>4, ln = lane&15;
  const int wrow = (wave>>1)*64, wcol = (wave&1)*64;

  f32x4_ acc[4][4];
#pragma unroll
  for (int i=0;i<4;i++)
#pragma unroll
    for (int j=0;j<4;j++) acc[i][j] = (f32x4_){0.f,0.f,0.f,0.f};

  const int arow = lane >> 3;                  // row within 8-row DMA chunk
  const int aseg = ((lane & 7) ^ arow) * 8;    // swizzled SOURCE segment (halfs)
  const int brow = tid >> 1;                   // 0..127
  const int bseg = (tid & 1) * 32;             // halfs

  for (int k0=0;k0<Kpad;k0+=64){
    // A: 4 wave-level DMA chunks of 8 rows x 64 halfs (=1 KB each)
#pragma unroll
    for (int i=0;i<4;i++){
      const __half* gp = A + ((size_t)(b0 + wave*32 + i*8 + arow)*T_ + t)*DC_ + k0 + aseg;
      gld_lds16(gp, &As[wave*32 + i*8][0]);
    }
    // B: 32 floats -> 32 halfs per thread
    {
      const float* ws = Wi + ((size_t)dir*G_ + g0 + brow)*KinW + k0 + bseg;
      __half tmp[32];
#pragma unroll
      for (int u=0;u<4;u++) load8_(ws + 8*u, KinW - (k0 + bseg + 8*u), tmp + 8*u);
#pragma unroll
      for (int u=0;u<4;u++) *(uint4*)&Bs[brow][bseg + 8*u] = *(uint4*)&tmp[8*u];
    }
    __syncthreads();
#pragma unroll
    for (int sub=0; sub<2; sub++){
      half8_ av[4], bv[4];
#pragma unroll
      for (int i=0;i<4;i++)
        av[i] = *(const half8_*)&As[wrow + i*16 + ln][(((sub*4 + quad) ^ (ln & 7)))*8];
#pragma unroll
      for (int j=0;j<4;j++)
        bv[j] = *(const half8_*)&Bs[wcol + j*16 + ln][sub*32 + quad*8];
#pragma unroll
      for (int i=0;i<4;i++)
#pragma unroll
        for (int j=0;j<4;j++)
          acc[i][j] = __builtin_amdgcn_mfma_f32_16x16x32_f16(av[i], bv[j], acc[i][j], 0, 0, 0);
    }
    __syncthreads();
  }
  float bj[4];
#pragma unroll
  for (int j=0;j<4;j++) bj[j] = bihL[dir*G_ + g0 + wcol + j*16 + ln];
  const size_t obase = (size_t)(dir*T_ + t)*C*(size_t)G_;
#pragma unroll
  for (int i=0;i<4;i++){
#pragma unroll
    for (int r=0;r<4;r++){
      int row = b0 + wrow + i*16 + quad*4 + r;
#pragma unroll
      for (int j=0;j<4;j++){
        int col = g0 + wcol + j*16 + ln;
        gx[obase + (size_t)row*G_ + col] = __float2half(acc[i][j][r] + bj[j]);
      }
    }
  }
}

// ---------------- GRU recurrence via MFMA (R10-proven, unchanged) ----------------
__global__ __launch_bounds__(512, 2) void k_gru_rec(
    const __half* __restrict__ gx,    // [2][T][C][G] fp16
    const __half* __restrict__ WFl,   // [2][8][48][64][8] fp16 (frag-packed)
    const float*  __restrict__ bhhL,  // [2][G] fp32
    __half* __restrict__ out,         // [C][T][DC] fp16; dir writes cols dir*H..dir*H+255
    float*  __restrict__ hsum,        // [2][C][H] fp32
    int init, int C)
{
  const int dir  = blockIdx.y;
  const int b0   = blockIdx.x * 16;
  const int tid  = threadIdx.x;
  const int wave = tid >> 6, lane = tid & 63;
  const int quad = lane >> 4, ln = lane & 15;

  __shared__ __half hsA[16][264];
  for (int i = tid; i < 16*264; i += 512) ((__half*)hsA)[i] = __ushort_as_half((unsigned short)0);

  float hreg[2][4];
#pragma unroll
  for (int i=0;i<2;i++)
#pragma unroll
    for (int r=0;r<4;r++) hreg[i][r] = 0.f;

  float bR[2], bZ[2], bN[2];
#pragma unroll
  for (int i=0;i<2;i++){
    int col = (wave + 8*i)*16 + ln;
    bR[i] = bhhL[dir*G_ + col];
    bZ[i] = bhhL[dir*G_ + H_  + col];
    bN[i] = bhhL[dir*G_ + 2*H_ + col];
  }

  const half8_* WF8 = (const half8_*)(WFl + (size_t)dir*WFLD_);

  half8_ wres[6][5];
#pragma unroll
  for (int kk=0;kk<5;kk++)
#pragma unroll
    for (int m=0;m<6;m++)
      wres[m][kk] = WF8[(size_t)(kk*48 + wave + 8*m)*64 + lane];

  __syncthreads();

  int ttprev = 0;
  for (int t=0;t<T_;t++){
    const int tt = dir ? (T_-1-t) : t;

    half8_ bf[2][6];
#pragma unroll
    for (int m=0;m<6;m++) bf[0][m] = WF8[(size_t)(5*48 + wave + 8*m)*64 + lane];
#pragma unroll
    for (int m=0;m<6;m++) bf[1][m] = WF8[(size_t)(6*48 + wave + 8*m)*64 + lane];

    if (t > 0){
#pragma unroll
      for (int i=0;i<2;i++){
        const int col = (wave + 8*i)*16 + ln;
#pragma unroll
        for (int r=0;r<4;r++){
          const int row = quad*4 + r;
          out[((size_t)(b0+row)*T_ + ttprev)*DC_ + dir*H_ + col] = __float2half(hreg[i][r]);
        }
      }
    }

    const __half* gxp = gx + ((size_t)(dir*T_ + tt)*C + b0)*G_;
    __half gxh[3][2][4];
#pragma unroll
    for (int i=0;i<2;i++){
      const int col = (wave + 8*i)*16 + ln;
#pragma unroll
      for (int r=0;r<4;r++){
        const __half* pb = gxp + (size_t)(quad*4+r)*G_ + col;
        gxh[0][i][r] = pb[0];
        gxh[1][i][r] = pb[H_];
        gxh[2][i][r] = pb[2*H_];
      }
    }

    f32x4_ acc[6];
#pragma unroll
    for (int m=0;m<6;m++) acc[m] = (f32x4_){0.f,0.f,0.f,0.f};
#pragma unroll
    for (int kk=0;kk<5;kk++){
      half8_ af = *(const half8_*)&hsA[ln][kk*32 + quad*8];
#pragma unroll
      for (int m=0;m<6;m++)
        acc[m] = __builtin_amdgcn_mfma_f32_16x16x32_f16(af, wres[m][kk], acc[m], 0, 0, 0);
    }
    {
      half8_ af = *(const half8_*)&hsA[ln][5*32 + quad*8];
#pragma unroll
      for (int m=0;m<6;m++)
        acc[m] = __builtin_amdgcn_mfma_f32_16x16x32_f16(af, bf[0][m], acc[m], 0, 0, 0);
    }
#pragma unroll
    for (int m=0;m<6;m++)
      bf[0][m] = WF8[(size_t)(7*48 + wave + 8*m)*64 + lane];
    {
      half8_ af = *(const half8_*)&hsA[ln][6*32 + quad*8];
#pragma unroll
      for (int m=0;m<6;m++)
        acc[m] = __builtin_amdgcn_mfma_f32_16x16x32_f16(af, bf[1][m], acc[m], 0, 0, 0);
    }
    {
      half8_ af = *(const half8_*)&hsA[ln][7*32 + quad*8];
#pragma unroll
      for (int m=0;m<6;m++)
        acc[m] = __builtin_amdgcn_mfma_f32_16x16x32_f16(af, bf[0][m], acc[m], 0, 0, 0);
    }

#pragma unroll
    for (int i=0;i<2;i++){
#pragma unroll
      for (int r=0;r<4;r++){
        float gr = __half2float(gxh[0][i][r]);
        float gz = __half2float(gxh[1][i][r]);
        float gn = __half2float(gxh[2][i][r]);
        float rr = sigmoidf_(gr + bR[i] + acc[i  ][r]);
        float zz = sigmoidf_(gz + bZ[i] + acc[2+i][r]);
        float nn = tanhf(gn + rr*(bN[i] + acc[4+i][r]));
        hreg[i][r] = (1.f - zz)*nn + zz*hreg[i][r];
      }
    }
    __syncthreads();
#pragma unroll
    for (int i=0;i<2;i++){
      const int col = (wave + 8*i)*16 + ln;
#pragma unroll
      for (int r=0;r<4;r++)
        hsA[quad*4 + r][col] = __float2half(hreg[i][r]);
    }
    __syncthreads();
    ttprev = tt;
  }

#pragma unroll
  for (int i=0;i<2;i++){
    const int col = (wave + 8*i)*16 + ln;
#pragma unroll
    for (int r=0;r<4;r++){
      const int row = quad*4 + r;
      out[((size_t)(b0+row)*T_ + ttprev)*DC_ + dir*H_ + col] = __float2half(hreg[i][r]);
      float* dst = &hsum[((size_t)dir*C + b0 + row)*H_ + col];
      if (init) *dst = hreg[i][r]; else *dst += hreg[i][r];
    }
  }
}

// ---------------- head (per chunk) ----------------
__global__ __launch_bounds__(256) void k_head(
    const float* __restrict__ hsum, // [2][C][H]
    const float* __restrict__ W1, const float* __restrict__ b1,
    const float* __restrict__ W2, const float* __restrict__ b2,
    const float* __restrict__ Wc, const float* __restrict__ bc,
    float* __restrict__ outp, int C)
{
  __shared__ float hb[4][H_];
  __shared__ float y1[4][64];
  __shared__ float y2[4][32];
  int w = threadIdx.x >> 6, lane = threadIdx.x & 63;
  int b = blockIdx.x*4 + w;
  for (int i=lane;i<H_;i+=64){
    float s = hsum[(size_t)b*H_ + i] + hsum[((size_t)C + b)*H_ + i];
    hb[w][i] = s * (1.f/16.f);
  }
  __syncthreads();
  {
    float s = b1[lane];
#pragma unroll 8
    for (int k=0;k<H_;k++) s = fmaf(W1[lane*H_ + k], hb[w][k], s);
    y1[w][lane] = s * (1.f/(1.f+expf(-s)));
  }
  __syncthreads();
  if (lane < 32){
    float s = b2[lane];
#pragma unroll
    for (int k=0;k<64;k++) s = fmaf(W2[lane*64 + k], y1[w][k], s);
    y2[w][lane] = s * (1.f/(1.f+expf(-s)));
  }
  __syncthreads();
  if (lane == 0){
    float s = bc[0];
#pragma unroll
    for (int k=0;k<32;k++) s = fmaf(Wc[k], y2[w][k], s);
    outp[b] = s;
  }
}

static inline size_t al256(size_t x){ return (x + 255) & ~(size_t)255; }

extern "C" void kernel_launch(void* const* d_in, const int* in_sizes, int n_in,
                              void* d_out, int out_size, void* d_ws, size_t ws_size,
                              hipStream_t stream)
{
  const float* x    = (const float*)d_in[0];
  const float* Wih0 = (const float*)d_in[1];
  const float* WihR = (const float*)d_in[2];
  const float* Whh  = (const float*)d_in[3];
  const float* bih  = (const float*)d_in[4];
  const float* bhh  = (const float*)d_in[5];
  const float* W1p  = (const float*)d_in[6];
  const float* b1p  = (const float*)d_in[7];
  const float* W2p  = (const float*)d_in[8];
  const float* b2p  = (const float*)d_in[9];
  const float* Wcp  = (const float*)d_in[10];
  const float* bcp  = (const float*)d_in[11];
  float* outp = (float*)d_out;
  (void)in_sizes; (void)n_in;

  auto need = [](int nc) -> size_t {
    size_t c = B_ / nc;
    size_t s = 0;
    s += al256((size_t)2*T_*c*G_*sizeof(__half));   // gx
    s += al256((size_t)c*T_*DC_*sizeof(__half));    // buf
    s += al256((size_t)16*H_*G_*sizeof(__half));    // WF
    s += al256((size_t)2*c*H_*sizeof(float));       // hsum
    return s;
  };
  const int ncs[5] = {1,2,4,8,16};
  int NC = 16; bool fits = false;
  for (int i=0;i<5;i++){ if (need(ncs[i]) <= ws_size){ NC = ncs[i]; fits = true; break; } }

  if (!fits){
    k_zero<<<(out_size + 255)/256, 256, 0, stream>>>(outp, out_size);
    return;
  }

  const size_t C = B_ / NC;
  char* p = (char*)d_ws;
  __half* gx   = (__half*)p;  p += al256((size_t)2*T_*C*G_*sizeof(__half));
  __half* buf  = (__half*)p;  p += al256((size_t)C*T_*DC_*sizeof(__half));
  __half* WF   = (__half*)p;  p += al256((size_t)16*H_*G_*sizeof(__half));
  float*  hsum = (float*)p;   p += al256((size_t)2*C*H_*sizeof(float));

  k_pack_whh<<<dim3(8, 48, 16), 64, 0, stream>>>(Whh, WF);

  for (int cc=0; cc<NC; cc++){
    const size_t b0c = (size_t)cc * C;
    // x fp32 -> buf f16 cols 0..191 (layer-0 A path; rec overwrites buf afterwards)
    k_cvt_x<<<(int)((C*T_*24 + 255)/256), 256, 0, stream>>>(x + b0c*T_*D0_, buf, (int)C);
    for (int l=0;l<L_;l++){
      const float* Wi = (l==0) ? Wih0 : (WihR + (size_t)(l-1)*2*G_*DC_);
      const int KinW  = (l==0) ? D0_ : DC_;
      const int Kpad  = (l==0) ? 192 : DC_;
      k_gx_mfma<<<dim3(C/128, G_/128, 2*T_), 256, 0, stream>>>(
          buf, Wi, bih + (size_t)l*2*G_, gx, (int)C, KinW, Kpad);
      k_gru_rec<<<dim3(C/16, 2), 512, 0, stream>>>(
          gx, WF + (size_t)l*2*WFLD_, bhh + (size_t)l*2*G_, buf,
          hsum, (l==0) ? 1 : 0, (int)C);
    }
    k_head<<<dim3(C/4), 256, 0, stream>>>(hsum, W1p,b1p,W2p,b2p,Wcp,bcp,
                                          outp + b0c, (int)C);
  }
}

// Round 13
// 1144.318 us; speedup vs baseline: 1.3626x; 1.3626x over previous
//
#include <hip/hip_runtime.h>
#include <hip/hip_fp16.h>
#include <cstdint>
#include <cstddef>

#define B_   2048
#define T_   13
#define D0_  188
#define H_   256
#define G_   768   // 3*H
#define L_   8
#define DC_  512   // 2*H concat width
#define WFLD_ (8*48*64*8)   // halfs per (layer,dir) in fragment-packed W_hh = 196608

typedef _Float16 half8_ __attribute__((ext_vector_type(8)));
typedef float    f32x4_ __attribute__((ext_vector_type(4)));

__device__ __forceinline__ float sigmoidf_(float x){ return 1.f/(1.f + expf(-x)); }

// async global->LDS, 16B per lane; LDS dest = wave-uniform base + lane*16 (m104/m108)
__device__ __forceinline__ void gld_lds16(const __half* g, __half* l){
  __builtin_amdgcn_global_load_lds(
      (const __attribute__((address_space(1))) void*)g,
      (__attribute__((address_space(3))) void*)l, 16, 0, 0);
}

// ---------------- fallback: zero d_out ----------------
__global__ __launch_bounds__(256) void k_zero(float* __restrict__ o, int n){
  int i = blockIdx.x*256 + threadIdx.x;
  if (i < n) o[i] = 0.f;
}

// ---------------- pack W_hh [16][G][H] fp32 -> MFMA B-fragment layout fp16 ----------------
__global__ __launch_bounds__(64) void k_pack_whh(const float* __restrict__ W,
                                                 __half* __restrict__ WF){
  int kk = blockIdx.x, c = blockIdx.y, ld = blockIdx.z;
  int lane = threadIdx.x, n = lane & 15, quad = lane >> 4;
  int col = c*16 + n;
  const float* src = W + ((size_t)ld*G_ + col)*H_ + kk*32 + quad*8;
  __half tmp[8];
#pragma unroll
  for (int j=0;j<8;j++) tmp[j] = __float2half(src[j]);
  *(uint4*)(WF + (size_t)ld*WFLD_ + (((size_t)kk*48 + c)*64 + lane)*8) = *(uint4*)tmp;
}

// ---------------- guarded fp32 -> 8 halfs ----------------
__device__ __forceinline__ void load8_(const float* s, int rem, __half* d){
  if (rem >= 8){
#pragma unroll
    for (int u=0;u<8;u++) d[u] = __float2half(s[u]);
  } else {
#pragma unroll
    for (int u=0;u<8;u++) d[u] = (u<rem) ? __float2half(s[u]) : __ushort_as_half((unsigned short)0);
  }
}

// ---------------- x fp32 [C][T][188] -> buf fp16 [C][T][512] cols 0..191 ----------------
__global__ __launch_bounds__(256) void k_cvt_x(const float* __restrict__ x,
                                               __half* __restrict__ buf, int C){
  int idx = blockIdx.x*256 + threadIdx.x;         // C*T*24 items of 8 halfs
  if (idx >= C*T_*24) return;
  int seg = (idx % 24) * 8;                       // 0..184
  int bt  = idx / 24;
  __half tmp[8];
  load8_(x + (size_t)bt*D0_ + seg, D0_ - seg, tmp);
  *(uint4*)&buf[(size_t)bt*DC_ + seg] = *(uint4*)tmp;
}

// ---------------- W_ih fp32 -> f16 [8][2][768][512] (layer0: cols 0..191, pad 188..191) ----
__global__ __launch_bounds__(256) void k_cvt_wih(const float* __restrict__ Wih0,
                                                 const float* __restrict__ WihR,
                                                 __half* __restrict__ Wh){
  int idx = blockIdx.x*256 + threadIdx.x;   // 8*2*768*64 items of 8 halfs
  if (idx >= 8*2*G_*64) return;
  int seg = (idx & 63) * 8;                 // 0..504
  int row = idx >> 6;                       // l*2*G + (dir*G+g)
  int l = row / (2*G_), r = row % (2*G_);
  __half tmp[8];
  if (l == 0){
    if (seg >= 192) return;                 // cols >=192 never read for layer 0
    load8_(Wih0 + (size_t)r*D0_ + seg, D0_ - seg, tmp);
  } else {
    load8_(WihR + ((size_t)(l-1)*2*G_ + r)*DC_ + seg, DC_ - seg, tmp);
  }
  *(uint4*)&Wh[(size_t)row*DC_ + seg] = *(uint4*)tmp;
}

// ---------------- gx GEMM, all-DMA staging: BM=128 BN=128 BK=64, 4 waves (64x64 each).
// A and B both staged via global_load_lds w=16 into XOR-swizzled [128][64] tiles:
// DMA lane l of an 8-row chunk SOURCES global segment ((l&7)^(l>>3))*8, so LDS seg s of
// row R holds global seg s^(R&7); readers index seg=(sub*4+quad)^(ln&7) -> 2-way banks.
// K-loop body: 8 wave-DMA + 2 barriers + 32 MFMA. Math order identical to R12.
__global__ __launch_bounds__(256) void k_gx_dma(
    const __half* __restrict__ A,    // [C][T][DC_] fp16
    const __half* __restrict__ Wh,   // [2][G][DC_] fp16 (this layer)
    const float* __restrict__ bihL,  // [2][G] fp32
    __half* __restrict__ gx,         // [2][T][C][G] fp16
    int C, int Kpad)
{
  __shared__ __align__(16) __half As[128][64];   // 16 KB
  __shared__ __align__(16) __half Bs[128][64];   // 16 KB
  const int dir = blockIdx.z / T_, t = blockIdx.z % T_;
  const int b0 = blockIdx.x*128, g0 = blockIdx.y*128;
  const int tid = threadIdx.x;
  const int wave = tid>>6, lane = tid&63;
  const int quad = lane>>4, ln = lane&15;
  const int wrow = (wave>>1)*64, wcol = (wave&1)*64;

  f32x4_ acc[4][4];
#pragma unroll
  for (int i=0;i<4;i++)
#pragma unroll
    for (int j=0;j<4;j++) acc[i][j] = (f32x4_){0.f,0.f,0.f,0.f};

  const int arow = lane >> 3;                  // row within 8-row DMA chunk
  const int aseg = ((lane & 7) ^ arow) * 8;    // swizzled SOURCE segment (halfs)

  for (int k0=0;k0<Kpad;k0+=64){
#pragma unroll
    for (int i=0;i<4;i++){
      const __half* gp = A + ((size_t)(b0 + wave*32 + i*8 + arow)*T_ + t)*DC_ + k0 + aseg;
      gld_lds16(gp, &As[wave*32 + i*8][0]);
      const __half* wp = Wh + ((size_t)dir*G_ + g0 + wave*32 + i*8 + arow)*DC_ + k0 + aseg;
      gld_lds16(wp, &Bs[wave*32 + i*8][0]);
    }
    __syncthreads();
#pragma unroll
    for (int sub=0; sub<2; sub++){
      half8_ av[4], bv[4];
#pragma unroll
      for (int i=0;i<4;i++)
        av[i] = *(const half8_*)&As[wrow + i*16 + ln][(((sub*4 + quad) ^ (ln & 7)))*8];
#pragma unroll
      for (int j=0;j<4;j++)
        bv[j] = *(const half8_*)&Bs[wcol + j*16 + ln][(((sub*4 + quad) ^ (ln & 7)))*8];
#pragma unroll
      for (int i=0;i<4;i++)
#pragma unroll
        for (int j=0;j<4;j++)
          acc[i][j] = __builtin_amdgcn_mfma_f32_16x16x32_f16(av[i], bv[j], acc[i][j], 0, 0, 0);
    }
    __syncthreads();
  }
  float bj[4];
#pragma unroll
  for (int j=0;j<4;j++) bj[j] = bihL[dir*G_ + g0 + wcol + j*16 + ln];
  const size_t obase = (size_t)(dir*T_ + t)*C*(size_t)G_;
#pragma unroll
  for (int i=0;i<4;i++){
#pragma unroll
    for (int r=0;r<4;r++){
      int row = b0 + wrow + i*16 + quad*4 + r;
#pragma unroll
      for (int j=0;j<4;j++){
        int col = g0 + wcol + j*16 + ln;
        gx[obase + (size_t)row*G_ + col] = __float2half(acc[i][j][r] + bj[j]);
      }
    }
  }
}

// ---------------- gx GEMM fallback (R12-proven, fp32 weights VALU-staged) ----------------
__global__ __launch_bounds__(256) void k_gx_mfma_f32w(
    const __half* __restrict__ A, const float* __restrict__ Wi,
    const float* __restrict__ bihL, __half* __restrict__ gx,
    int C, int KinW, int Kpad)
{
  __shared__ __align__(16) __half As[128][64];
  __shared__ __align__(16) __half Bs[128][72];
  const int dir = blockIdx.z / T_, t = blockIdx.z % T_;
  const int b0 = blockIdx.x*128, g0 = blockIdx.y*128;
  const int tid = threadIdx.x;
  const int wave = tid>>6, lane = tid&63;
  const int quad = lane>>4, ln = lane&15;
  const int wrow = (wave>>1)*64, wcol = (wave&1)*64;
  f32x4_ acc[4][4];
#pragma unroll
  for (int i=0;i<4;i++)
#pragma unroll
    for (int j=0;j<4;j++) acc[i][j] = (f32x4_){0.f,0.f,0.f,0.f};
  const int arow = lane >> 3;
  const int aseg = ((lane & 7) ^ arow) * 8;
  const int brow = tid >> 1;
  const int bseg = (tid & 1) * 32;
  for (int k0=0;k0<Kpad;k0+=64){
#pragma unroll
    for (int i=0;i<4;i++){
      const __half* gp = A + ((size_t)(b0 + wave*32 + i*8 + arow)*T_ + t)*DC_ + k0 + aseg;
      gld_lds16(gp, &As[wave*32 + i*8][0]);
    }
    {
      const float* ws = Wi + ((size_t)dir*G_ + g0 + brow)*KinW + k0 + bseg;
      __half tmp[32];
#pragma unroll
      for (int u=0;u<4;u++) load8_(ws + 8*u, KinW - (k0 + bseg + 8*u), tmp + 8*u);
#pragma unroll
      for (int u=0;u<4;u++) *(uint4*)&Bs[brow][bseg + 8*u] = *(uint4*)&tmp[8*u];
    }
    __syncthreads();
#pragma unroll
    for (int sub=0; sub<2; sub++){
      half8_ av[4], bv[4];
#pragma unroll
      for (int i=0;i<4;i++)
        av[i] = *(const half8_*)&As[wrow + i*16 + ln][(((sub*4 + quad) ^ (ln & 7)))*8];
#pragma unroll
      for (int j=0;j<4;j++)
        bv[j] = *(const half8_*)&Bs[wcol + j*16 + ln][sub*32 + quad*8];
#pragma unroll
      for (int i=0;i<4;i++)
#pragma unroll
        for (int j=0;j<4;j++)
          acc[i][j] = __builtin_amdgcn_mfma_f32_16x16x32_f16(av[i], bv[j], acc[i][j], 0, 0, 0);
    }
    __syncthreads();
  }
  float bj[4];
#pragma unroll
  for (int j=0;j<4;j++) bj[j] = bihL[dir*G_ + g0 + wcol + j*16 + ln];
  const size_t obase = (size_t)(dir*T_ + t)*C*(size_t)G_;
#pragma unroll
  for (int i=0;i<4;i++){
#pragma unroll
    for (int r=0;r<4;r++){
      int row = b0 + wrow + i*16 + quad*4 + r;
#pragma unroll
      for (int j=0;j<4;j++){
        int col = g0 + wcol + j*16 + ln;
        gx[obase + (size_t)row*G_ + col] = __float2half(acc[i][j][r] + bj[j]);
      }
    }
  }
}

// ---------------- GRU recurrence via MFMA (R10-proven, unchanged) ----------------
__global__ __launch_bounds__(512, 2) void k_gru_rec(
    const __half* __restrict__ gx, const __half* __restrict__ WFl,
    const float* __restrict__ bhhL, __half* __restrict__ out,
    float* __restrict__ hsum, int init, int C)
{
  const int dir  = blockIdx.y;
  const int b0   = blockIdx.x * 16;
  const int tid  = threadIdx.x;
  const int wave = tid >> 6, lane = tid & 63;
  const int quad = lane >> 4, ln = lane & 15;

  __shared__ __half hsA[16][264];
  for (int i = tid; i < 16*264; i += 512) ((__half*)hsA)[i] = __ushort_as_half((unsigned short)0);

  float hreg[2][4];
#pragma unroll
  for (int i=0;i<2;i++)
#pragma unroll
    for (int r=0;r<4;r++) hreg[i][r] = 0.f;

  float bR[2], bZ[2], bN[2];
#pragma unroll
  for (int i=0;i<2;i++){
    int col = (wave + 8*i)*16 + ln;
    bR[i] = bhhL[dir*G_ + col];
    bZ[i] = bhhL[dir*G_ + H_  + col];
    bN[i] = bhhL[dir*G_ + 2*H_ + col];
  }

  const half8_* WF8 = (const half8_*)(WFl + (size_t)dir*WFLD_);

  half8_ wres[6][5];
#pragma unroll
  for (int kk=0;kk<5;kk++)
#pragma unroll
    for (int m=0;m<6;m++)
      wres[m][kk] = WF8[(size_t)(kk*48 + wave + 8*m)*64 + lane];

  __syncthreads();

  int ttprev = 0;
  for (int t=0;t<T_;t++){
    const int tt = dir ? (T_-1-t) : t;

    half8_ bf[2][6];
#pragma unroll
    for (int m=0;m<6;m++) bf[0][m] = WF8[(size_t)(5*48 + wave + 8*m)*64 + lane];
#pragma unroll
    for (int m=0;m<6;m++) bf[1][m] = WF8[(size_t)(6*48 + wave + 8*m)*64 + lane];

    if (t > 0){
#pragma unroll
      for (int i=0;i<2;i++){
        const int col = (wave + 8*i)*16 + ln;
#pragma unroll
        for (int r=0;r<4;r++){
          const int row = quad*4 + r;
          out[((size_t)(b0+row)*T_ + ttprev)*DC_ + dir*H_ + col] = __float2half(hreg[i][r]);
        }
      }
    }

    const __half* gxp = gx + ((size_t)(dir*T_ + tt)*C + b0)*G_;
    __half gxh[3][2][4];
#pragma unroll
    for (int i=0;i<2;i++){
      const int col = (wave + 8*i)*16 + ln;
#pragma unroll
      for (int r=0;r<4;r++){
        const __half* pb = gxp + (size_t)(quad*4+r)*G_ + col;
        gxh[0][i][r] = pb[0];
        gxh[1][i][r] = pb[H_];
        gxh[2][i][r] = pb[2*H_];
      }
    }

    f32x4_ acc[6];
#pragma unroll
    for (int m=0;m<6;m++) acc[m] = (f32x4_){0.f,0.f,0.f,0.f};
#pragma unroll
    for (int kk=0;kk<5;kk++){
      half8_ af = *(const half8_*)&hsA[ln][kk*32 + quad*8];
#pragma unroll
      for (int m=0;m<6;m++)
        acc[m] = __builtin_amdgcn_mfma_f32_16x16x32_f16(af, wres[m][kk], acc[m], 0, 0, 0);
    }
    {
      half8_ af = *(const half8_*)&hsA[ln][5*32 + quad*8];
#pragma unroll
      for (int m=0;m<6;m++)
        acc[m] = __builtin_amdgcn_mfma_f32_16x16x32_f16(af, bf[0][m], acc[m], 0, 0, 0);
    }
#pragma unroll
    for (int m=0;m<6;m++)
      bf[0][m] = WF8[(size_t)(7*48 + wave + 8*m)*64 + lane];
    {
      half8_ af = *(const half8_*)&hsA[ln][6*32 + quad*8];
#pragma unroll
      for (int m=0;m<6;m++)
        acc[m] = __builtin_amdgcn_mfma_f32_16x16x32_f16(af, bf[1][m], acc[m], 0, 0, 0);
    }
    {
      half8_ af = *(const half8_*)&hsA[ln][7*32 + quad*8];
#pragma unroll
      for (int m=0;m<6;m++)
        acc[m] = __builtin_amdgcn_mfma_f32_16x16x32_f16(af, bf[0][m], acc[m], 0, 0, 0);
    }

#pragma unroll
    for (int i=0;i<2;i++){
#pragma unroll
      for (int r=0;r<4;r++){
        float gr = __half2float(gxh[0][i][r]);
        float gz = __half2float(gxh[1][i][r]);
        float gn = __half2float(gxh[2][i][r]);
        float rr = sigmoidf_(gr + bR[i] + acc[i  ][r]);
        float zz = sigmoidf_(gz + bZ[i] + acc[2+i][r]);
        float nn = tanhf(gn + rr*(bN[i] + acc[4+i][r]));
        hreg[i][r] = (1.f - zz)*nn + zz*hreg[i][r];
      }
    }
    __syncthreads();
#pragma unroll
    for (int i=0;i<2;i++){
      const int col = (wave + 8*i)*16 + ln;
#pragma unroll
      for (int r=0;r<4;r++)
        hsA[quad*4 + r][col] = __float2half(hreg[i][r]);
    }
    __syncthreads();
    ttprev = tt;
  }

#pragma unroll
  for (int i=0;i<2;i++){
    const int col = (wave + 8*i)*16 + ln;
#pragma unroll
    for (int r=0;r<4;r++){
      const int row = quad*4 + r;
      out[((size_t)(b0+row)*T_ + ttprev)*DC_ + dir*H_ + col] = __float2half(hreg[i][r]);
      float* dst = &hsum[((size_t)dir*C + b0 + row)*H_ + col];
      if (init) *dst = hreg[i][r]; else *dst += hreg[i][r];
    }
  }
}

// ---------------- head (per chunk) ----------------
__global__ __launch_bounds__(256) void k_head(
    const float* __restrict__ hsum,
    const float* __restrict__ W1, const float* __restrict__ b1,
    const float* __restrict__ W2, const float* __restrict__ b2,
    const float* __restrict__ Wc, const float* __restrict__ bc,
    float* __restrict__ outp, int C)
{
  __shared__ float hb[4][H_];
  __shared__ float y1[4][64];
  __shared__ float y2[4][32];
  int w = threadIdx.x >> 6, lane = threadIdx.x & 63;
  int b = blockIdx.x*4 + w;
  for (int i=lane;i<H_;i+=64){
    float s = hsum[(size_t)b*H_ + i] + hsum[((size_t)C + b)*H_ + i];
    hb[w][i] = s * (1.f/16.f);
  }
  __syncthreads();
  {
    float s = b1[lane];
#pragma unroll 8
    for (int k=0;k<H_;k++) s = fmaf(W1[lane*H_ + k], hb[w][k], s);
    y1[w][lane] = s * (1.f/(1.f+expf(-s)));
  }
  __syncthreads();
  if (lane < 32){
    float s = b2[lane];
#pragma unroll
    for (int k=0;k<64;k++) s = fmaf(W2[lane*64 + k], y1[w][k], s);
    y2[w][lane] = s * (1.f/(1.f+expf(-s)));
  }
  __syncthreads();
  if (lane == 0){
    float s = bc[0];
#pragma unroll
    for (int k=0;k<32;k++) s = fmaf(Wc[k], y2[w][k], s);
    outp[b] = s;
  }
}

static inline size_t al256(size_t x){ return (x + 255) & ~(size_t)255; }

extern "C" void kernel_launch(void* const* d_in, const int* in_sizes, int n_in,
                              void* d_out, int out_size, void* d_ws, size_t ws_size,
                              hipStream_t stream)
{
  const float* x    = (const float*)d_in[0];
  const float* Wih0 = (const float*)d_in[1];
  const float* WihR = (const float*)d_in[2];
  const float* Whh  = (const float*)d_in[3];
  const float* bih  = (const float*)d_in[4];
  const float* bhh  = (const float*)d_in[5];
  const float* W1p  = (const float*)d_in[6];
  const float* b1p  = (const float*)d_in[7];
  const float* W2p  = (const float*)d_in[8];
  const float* b2p  = (const float*)d_in[9];
  const float* Wcp  = (const float*)d_in[10];
  const float* bcp  = (const float*)d_in[11];
  float* outp = (float*)d_out;
  (void)in_sizes; (void)n_in;

  auto need_basic = [](int nc) -> size_t {
    size_t c = B_ / nc;
    size_t s = 0;
    s += al256((size_t)2*T_*c*G_*sizeof(__half));   // gx
    s += al256((size_t)c*T_*DC_*sizeof(__half));    // buf
    s += al256((size_t)16*H_*G_*sizeof(__half));    // WF
    s += al256((size_t)2*c*H_*sizeof(float));       // hsum
    return s;
  };
  const size_t wih_bytes = al256((size_t)8*2*G_*DC_*sizeof(__half));  // 12.6 MB
  const bool full = (need_basic(1) + wih_bytes) <= ws_size;           // all-DMA path

  int NC = 1; bool fits = full;
  if (!full){
    const int ncs[5] = {1,2,4,8,16};
    for (int i=0;i<5;i++){ if (need_basic(ncs[i]) <= ws_size){ NC = ncs[i]; fits = true; break; } }
  }
  if (!fits){
    k_zero<<<(out_size + 255)/256, 256, 0, stream>>>(outp, out_size);
    return;
  }

  const size_t C = B_ / NC;
  char* p = (char*)d_ws;
  __half* gx   = (__half*)p;  p += al256((size_t)2*T_*C*G_*sizeof(__half));
  __half* buf  = (__half*)p;  p += al256((size_t)C*T_*DC_*sizeof(__half));
  __half* WF   = (__half*)p;  p += al256((size_t)16*H_*G_*sizeof(__half));
  float*  hsum = (float*)p;   p += al256((size_t)2*C*H_*sizeof(float));
  __half* Wh   = (__half*)p;  // only valid on full path

  k_pack_whh<<<dim3(8, 48, 16), 64, 0, stream>>>(Whh, WF);
  if (full)
    k_cvt_wih<<<(8*2*G_*64 + 255)/256, 256, 0, stream>>>(Wih0, WihR, Wh);

  for (int cc=0; cc<NC; cc++){
    const size_t b0c = (size_t)cc * C;
    k_cvt_x<<<(int)((C*T_*24 + 255)/256), 256, 0, stream>>>(x + b0c*T_*D0_, buf, (int)C);
    for (int l=0;l<L_;l++){
      const int Kpad = (l==0) ? 192 : DC_;
      if (full){
        k_gx_dma<<<dim3(C/128, G_/128, 2*T_), 256, 0, stream>>>(
            buf, Wh + (size_t)l*2*G_*DC_, bih + (size_t)l*2*G_, gx, (int)C, Kpad);
      } else {
        const float* Wi = (l==0) ? Wih0 : (WihR + (size_t)(l-1)*2*G_*DC_);
        const int KinW  = (l==0) ? D0_ : DC_;
        k_gx_mfma_f32w<<<dim3(C/128, G_/128, 2*T_), 256, 0, stream>>>(
            buf, Wi, bih + (size_t)l*2*G_, gx, (int)C, KinW, Kpad);
      }
      k_gru_rec<<<dim3(C/16, 2), 512, 0, stream>>>(
          gx, WF + (size_t)l*2*WFLD_, bhh + (size_t)l*2*G_, buf,
          hsum, (l==0) ? 1 : 0, (int)C);
    }
    k_head<<<dim3(C/4), 256, 0, stream>>>(hsum, W1p,b1p,W2p,b2p,Wcp,bcp,
                                          outp + b0c, (int)C);
  }
}

// Round 14
// 1011.143 us; speedup vs baseline: 1.5421x; 1.1317x over previous
//
#include <hip/hip_runtime.h>
#include <hip/hip_fp16.h>
#include <cstdint>
#include <cstddef>

#define B_   2048
#define T_   13
#define D0_  188
#define H_   256
#define G_   768   // 3*H
#define L_   8
#define DC_  512   // 2*H concat width
#define WFLD_ (8*48*64*8)   // halfs per (layer,dir) in fragment-packed W_hh = 196608

typedef _Float16 half8_ __attribute__((ext_vector_type(8)));
typedef float    f32x4_ __attribute__((ext_vector_type(4)));

__device__ __forceinline__ float sigmoidf_(float x){ return 1.f/(1.f + expf(-x)); }

// fast gate transcendentals (rec only): exp2/rcp HW ops, ~1e-6 abs err, exact at +-inf
__device__ __forceinline__ float fsigmoid_(float x){
  return __builtin_amdgcn_rcpf(1.f + __builtin_amdgcn_exp2f(-1.44269504089f * x));
}
__device__ __forceinline__ float ftanh_(float x){
  return 1.f - 2.f*__builtin_amdgcn_rcpf(1.f + __builtin_amdgcn_exp2f(2.88539008178f * x));
}

// async global->LDS, 16B per lane; LDS dest = wave-uniform base + lane*16 (m104/m108)
__device__ __forceinline__ void gld_lds16(const __half* g, __half* l){
  __builtin_amdgcn_global_load_lds(
      (const __attribute__((address_space(1))) void*)g,
      (__attribute__((address_space(3))) void*)l, 16, 0, 0);
}

// ---------------- fallback: zero d_out ----------------
__global__ __launch_bounds__(256) void k_zero(float* __restrict__ o, int n){
  int i = blockIdx.x*256 + threadIdx.x;
  if (i < n) o[i] = 0.f;
}

// ---------------- pack W_hh [16][G][H] fp32 -> MFMA B-fragment layout fp16 ----------------
__global__ __launch_bounds__(64) void k_pack_whh(const float* __restrict__ W,
                                                 __half* __restrict__ WF){
  int kk = blockIdx.x, c = blockIdx.y, ld = blockIdx.z;
  int lane = threadIdx.x, n = lane & 15, quad = lane >> 4;
  int col = c*16 + n;
  const float* src = W + ((size_t)ld*G_ + col)*H_ + kk*32 + quad*8;
  __half tmp[8];
#pragma unroll
  for (int j=0;j<8;j++) tmp[j] = __float2half(src[j]);
  *(uint4*)(WF + (size_t)ld*WFLD_ + (((size_t)kk*48 + c)*64 + lane)*8) = *(uint4*)tmp;
}

// ---------------- guarded fp32 -> 8 halfs ----------------
__device__ __forceinline__ void load8_(const float* s, int rem, __half* d){
  if (rem >= 8){
#pragma unroll
    for (int u=0;u<8;u++) d[u] = __float2half(s[u]);
  } else {
#pragma unroll
    for (int u=0;u<8;u++) d[u] = (u<rem) ? __float2half(s[u]) : __ushort_as_half((unsigned short)0);
  }
}

// ---------------- x fp32 [C][T][188] -> buf fp16 [C][T][512] cols 0..191 ----------------
__global__ __launch_bounds__(256) void k_cvt_x(const float* __restrict__ x,
                                               __half* __restrict__ buf, int C){
  int idx = blockIdx.x*256 + threadIdx.x;         // C*T*24 items of 8 halfs
  if (idx >= C*T_*24) return;
  int seg = (idx % 24) * 8;                       // 0..184
  int bt  = idx / 24;
  __half tmp[8];
  load8_(x + (size_t)bt*D0_ + seg, D0_ - seg, tmp);
  *(uint4*)&buf[(size_t)bt*DC_ + seg] = *(uint4*)tmp;
}

// ---------------- W_ih fp32 -> f16 [8][2][768][512] (layer0: cols 0..191, pad 188..191) ----
__global__ __launch_bounds__(256) void k_cvt_wih(const float* __restrict__ Wih0,
                                                 const float* __restrict__ WihR,
                                                 __half* __restrict__ Wh){
  int idx = blockIdx.x*256 + threadIdx.x;   // 8*2*768*64 items of 8 halfs
  if (idx >= 8*2*G_*64) return;
  int seg = (idx & 63) * 8;                 // 0..504
  int row = idx >> 6;                       // l*2*G + (dir*G+g)
  int l = row / (2*G_), r = row % (2*G_);
  __half tmp[8];
  if (l == 0){
    if (seg >= 192) return;                 // cols >=192 never read for layer 0
    load8_(Wih0 + (size_t)r*D0_ + seg, D0_ - seg, tmp);
  } else {
    load8_(WihR + ((size_t)(l-1)*2*G_ + r)*DC_ + seg, DC_ - seg, tmp);
  }
  *(uint4*)&Wh[(size_t)row*DC_ + seg] = *(uint4*)tmp;
}

// ---------------- gx GEMM, all-DMA staging (R13-proven, unchanged) ----------------
__global__ __launch_bounds__(256) void k_gx_dma(
    const __half* __restrict__ A,    // [C][T][DC_] fp16
    const __half* __restrict__ Wh,   // [2][G][DC_] fp16 (this layer)
    const float* __restrict__ bihL,  // [2][G] fp32
    __half* __restrict__ gx,         // [2][T][C][G] fp16
    int C, int Kpad)
{
  __shared__ __align__(16) __half As[128][64];   // 16 KB
  __shared__ __align__(16) __half Bs[128][64];   // 16 KB
  const int dir = blockIdx.z / T_, t = blockIdx.z % T_;
  const int b0 = blockIdx.x*128, g0 = blockIdx.y*128;
  const int tid = threadIdx.x;
  const int wave = tid>>6, lane = tid&63;
  const int quad = lane>>4, ln = lane&15;
  const int wrow = (wave>>1)*64, wcol = (wave&1)*64;

  f32x4_ acc[4][4];
#pragma unroll
  for (int i=0;i<4;i++)
#pragma unroll
    for (int j=0;j<4;j++) acc[i][j] = (f32x4_){0.f,0.f,0.f,0.f};

  const int arow = lane >> 3;                  // row within 8-row DMA chunk
  const int aseg = ((lane & 7) ^ arow) * 8;    // swizzled SOURCE segment (halfs)

  for (int k0=0;k0<Kpad;k0+=64){
#pragma unroll
    for (int i=0;i<4;i++){
      const __half* gp = A + ((size_t)(b0 + wave*32 + i*8 + arow)*T_ + t)*DC_ + k0 + aseg;
      gld_lds16(gp, &As[wave*32 + i*8][0]);
      const __half* wp = Wh + ((size_t)dir*G_ + g0 + wave*32 + i*8 + arow)*DC_ + k0 + aseg;
      gld_lds16(wp, &Bs[wave*32 + i*8][0]);
    }
    __syncthreads();
#pragma unroll
    for (int sub=0; sub<2; sub++){
      half8_ av[4], bv[4];
#pragma unroll
      for (int i=0;i<4;i++)
        av[i] = *(const half8_*)&As[wrow + i*16 + ln][(((sub*4 + quad) ^ (ln & 7)))*8];
#pragma unroll
      for (int j=0;j<4;j++)
        bv[j] = *(const half8_*)&Bs[wcol + j*16 + ln][(((sub*4 + quad) ^ (ln & 7)))*8];
#pragma unroll
      for (int i=0;i<4;i++)
#pragma unroll
        for (int j=0;j<4;j++)
          acc[i][j] = __builtin_amdgcn_mfma_f32_16x16x32_f16(av[i], bv[j], acc[i][j], 0, 0, 0);
    }
    __syncthreads();
  }
  float bj[4];
#pragma unroll
  for (int j=0;j<4;j++) bj[j] = bihL[dir*G_ + g0 + wcol + j*16 + ln];
  const size_t obase = (size_t)(dir*T_ + t)*C*(size_t)G_;
#pragma unroll
  for (int i=0;i<4;i++){
#pragma unroll
    for (int r=0;r<4;r++){
      int row = b0 + wrow + i*16 + quad*4 + r;
#pragma unroll
      for (int j=0;j<4;j++){
        int col = g0 + wcol + j*16 + ln;
        gx[obase + (size_t)row*G_ + col] = __float2half(acc[i][j][r] + bj[j]);
      }
    }
  }
}

// ---------------- gx GEMM fallback (R12-proven, fp32 weights VALU-staged) ----------------
__global__ __launch_bounds__(256) void k_gx_mfma_f32w(
    const __half* __restrict__ A, const float* __restrict__ Wi,
    const float* __restrict__ bihL, __half* __restrict__ gx,
    int C, int KinW, int Kpad)
{
  __shared__ __align__(16) __half As[128][64];
  __shared__ __align__(16) __half Bs[128][72];
  const int dir = blockIdx.z / T_, t = blockIdx.z % T_;
  const int b0 = blockIdx.x*128, g0 = blockIdx.y*128;
  const int tid = threadIdx.x;
  const int wave = tid>>6, lane = tid&63;
  const int quad = lane>>4, ln = lane&15;
  const int wrow = (wave>>1)*64, wcol = (wave&1)*64;
  f32x4_ acc[4][4];
#pragma unroll
  for (int i=0;i<4;i++)
#pragma unroll
    for (int j=0;j<4;j++) acc[i][j] = (f32x4_){0.f,0.f,0.f,0.f};
  const int arow = lane >> 3;
  const int aseg = ((lane & 7) ^ arow) * 8;
  const int brow = tid >> 1;
  const int bseg = (tid & 1) * 32;
  for (int k0=0;k0<Kpad;k0+=64){
#pragma unroll
    for (int i=0;i<4;i++){
      const __half* gp = A + ((size_t)(b0 + wave*32 + i*8 + arow)*T_ + t)*DC_ + k0 + aseg;
      gld_lds16(gp, &As[wave*32 + i*8][0]);
    }
    {
      const float* ws = Wi + ((size_t)dir*G_ + g0 + brow)*KinW + k0 + bseg;
      __half tmp[32];
#pragma unroll
      for (int u=0;u<4;u++) load8_(ws + 8*u, KinW - (k0 + bseg + 8*u), tmp + 8*u);
#pragma unroll
      for (int u=0;u<4;u++) *(uint4*)&Bs[brow][bseg + 8*u] = *(uint4*)&tmp[8*u];
    }
    __syncthreads();
#pragma unroll
    for (int sub=0; sub<2; sub++){
      half8_ av[4], bv[4];
#pragma unroll
      for (int i=0;i<4;i++)
        av[i] = *(const half8_*)&As[wrow + i*16 + ln][(((sub*4 + quad) ^ (ln & 7)))*8];
#pragma unroll
      for (int j=0;j<4;j++)
        bv[j] = *(const half8_*)&Bs[wcol + j*16 + ln][sub*32 + quad*8];
#pragma unroll
      for (int i=0;i<4;i++)
#pragma unroll
        for (int j=0;j<4;j++)
          acc[i][j] = __builtin_amdgcn_mfma_f32_16x16x32_f16(av[i], bv[j], acc[i][j], 0, 0, 0);
    }
    __syncthreads();
  }
  float bj[4];
#pragma unroll
  for (int j=0;j<4;j++) bj[j] = bihL[dir*G_ + g0 + wcol + j*16 + ln];
  const size_t obase = (size_t)(dir*T_ + t)*C*(size_t)G_;
#pragma unroll
  for (int i=0;i<4;i++){
#pragma unroll
    for (int r=0;r<4;r++){
      int row = b0 + wrow + i*16 + quad*4 + r;
#pragma unroll
      for (int j=0;j<4;j++){
        int col = g0 + wcol + j*16 + ln;
        gx[obase + (size_t)row*G_ + col] = __float2half(acc[i][j][r] + bj[j]);
      }
    }
  }
}

// ---------------- GRU recurrence via MFMA (R10/R13 structure; fast gate transcendentals) ----
__global__ __launch_bounds__(512, 2) void k_gru_rec(
    const __half* __restrict__ gx, const __half* __restrict__ WFl,
    const float* __restrict__ bhhL, __half* __restrict__ out,
    float* __restrict__ hsum, int init, int C)
{
  const int dir  = blockIdx.y;
  const int b0   = blockIdx.x * 16;
  const int tid  = threadIdx.x;
  const int wave = tid >> 6, lane = tid & 63;
  const int quad = lane >> 4, ln = lane & 15;

  __shared__ __half hsA[16][264];
  for (int i = tid; i < 16*264; i += 512) ((__half*)hsA)[i] = __ushort_as_half((unsigned short)0);

  float hreg[2][4];
#pragma unroll
  for (int i=0;i<2;i++)
#pragma unroll
    for (int r=0;r<4;r++) hreg[i][r] = 0.f;

  float bR[2], bZ[2], bN[2];
#pragma unroll
  for (int i=0;i<2;i++){
    int col = (wave + 8*i)*16 + ln;
    bR[i] = bhhL[dir*G_ + col];
    bZ[i] = bhhL[dir*G_ + H_  + col];
    bN[i] = bhhL[dir*G_ + 2*H_ + col];
  }

  const half8_* WF8 = (const half8_*)(WFl + (size_t)dir*WFLD_);

  half8_ wres[6][5];
#pragma unroll
  for (int kk=0;kk<5;kk++)
#pragma unroll
    for (int m=0;m<6;m++)
      wres[m][kk] = WF8[(size_t)(kk*48 + wave + 8*m)*64 + lane];

  __syncthreads();

  int ttprev = 0;
  for (int t=0;t<T_;t++){
    const int tt = dir ? (T_-1-t) : t;

    half8_ bf[2][6];
#pragma unroll
    for (int m=0;m<6;m++) bf[0][m] = WF8[(size_t)(5*48 + wave + 8*m)*64 + lane];
#pragma unroll
    for (int m=0;m<6;m++) bf[1][m] = WF8[(size_t)(6*48 + wave + 8*m)*64 + lane];

    if (t > 0){
#pragma unroll
      for (int i=0;i<2;i++){
        const int col = (wave + 8*i)*16 + ln;
#pragma unroll
        for (int r=0;r<4;r++){
          const int row = quad*4 + r;
          out[((size_t)(b0+row)*T_ + ttprev)*DC_ + dir*H_ + col] = __float2half(hreg[i][r]);
        }
      }
    }

    const __half* gxp = gx + ((size_t)(dir*T_ + tt)*C + b0)*G_;
    __half gxh[3][2][4];
#pragma unroll
    for (int i=0;i<2;i++){
      const int col = (wave + 8*i)*16 + ln;
#pragma unroll
      for (int r=0;r<4;r++){
        const __half* pb = gxp + (size_t)(quad*4+r)*G_ + col;
        gxh[0][i][r] = pb[0];
        gxh[1][i][r] = pb[H_];
        gxh[2][i][r] = pb[2*H_];
      }
    }

    f32x4_ acc[6];
#pragma unroll
    for (int m=0;m<6;m++) acc[m] = (f32x4_){0.f,0.f,0.f,0.f};
#pragma unroll
    for (int kk=0;kk<5;kk++){
      half8_ af = *(const half8_*)&hsA[ln][kk*32 + quad*8];
#pragma unroll
      for (int m=0;m<6;m++)
        acc[m] = __builtin_amdgcn_mfma_f32_16x16x32_f16(af, wres[m][kk], acc[m], 0, 0, 0);
    }
    {
      half8_ af = *(const half8_*)&hsA[ln][5*32 + quad*8];
#pragma unroll
      for (int m=0;m<6;m++)
        acc[m] = __builtin_amdgcn_mfma_f32_16x16x32_f16(af, bf[0][m], acc[m], 0, 0, 0);
    }
#pragma unroll
    for (int m=0;m<6;m++)
      bf[0][m] = WF8[(size_t)(7*48 + wave + 8*m)*64 + lane];
    {
      half8_ af = *(const half8_*)&hsA[ln][6*32 + quad*8];
#pragma unroll
      for (int m=0;m<6;m++)
        acc[m] = __builtin_amdgcn_mfma_f32_16x16x32_f16(af, bf[1][m], acc[m], 0, 0, 0);
    }
    {
      half8_ af = *(const half8_*)&hsA[ln][7*32 + quad*8];
#pragma unroll
      for (int m=0;m<6;m++)
        acc[m] = __builtin_amdgcn_mfma_f32_16x16x32_f16(af, bf[0][m], acc[m], 0, 0, 0);
    }

    // gate phase: fast exp2/rcp transcendentals (only numeric change vs R13)
#pragma unroll
    for (int i=0;i<2;i++){
#pragma unroll
      for (int r=0;r<4;r++){
        float gr = __half2float(gxh[0][i][r]);
        float gz = __half2float(gxh[1][i][r]);
        float gn = __half2float(gxh[2][i][r]);
        float rr = fsigmoid_(gr + bR[i] + acc[i  ][r]);
        float zz = fsigmoid_(gz + bZ[i] + acc[2+i][r]);
        float nn = ftanh_(gn + rr*(bN[i] + acc[4+i][r]));   // b_hn inside r* (PyTorch semantics)
        hreg[i][r] = (1.f - zz)*nn + zz*hreg[i][r];
      }
    }
    __syncthreads();
#pragma unroll
    for (int i=0;i<2;i++){
      const int col = (wave + 8*i)*16 + ln;
#pragma unroll
      for (int r=0;r<4;r++)
        hsA[quad*4 + r][col] = __float2half(hreg[i][r]);
    }
    __syncthreads();
    ttprev = tt;
  }

#pragma unroll
  for (int i=0;i<2;i++){
    const int col = (wave + 8*i)*16 + ln;
#pragma unroll
    for (int r=0;r<4;r++){
      const int row = quad*4 + r;
      out[((size_t)(b0+row)*T_ + ttprev)*DC_ + dir*H_ + col] = __float2half(hreg[i][r]);
      float* dst = &hsum[((size_t)dir*C + b0 + row)*H_ + col];
      if (init) *dst = hreg[i][r]; else *dst += hreg[i][r];
    }
  }
}

// ---------------- head (per chunk, unchanged) ----------------
__global__ __launch_bounds__(256) void k_head(
    const float* __restrict__ hsum,
    const float* __restrict__ W1, const float* __restrict__ b1,
    const float* __restrict__ W2, const float* __restrict__ b2,
    const float* __restrict__ Wc, const float* __restrict__ bc,
    float* __restrict__ outp, int C)
{
  __shared__ float hb[4][H_];
  __shared__ float y1[4][64];
  __shared__ float y2[4][32];
  int w = threadIdx.x >> 6, lane = threadIdx.x & 63;
  int b = blockIdx.x*4 + w;
  for (int i=lane;i<H_;i+=64){
    float s = hsum[(size_t)b*H_ + i] + hsum[((size_t)C + b)*H_ + i];
    hb[w][i] = s * (1.f/16.f);
  }
  __syncthreads();
  {
    float s = b1[lane];
#pragma unroll 8
    for (int k=0;k<H_;k++) s = fmaf(W1[lane*H_ + k], hb[w][k], s);
    y1[w][lane] = s * (1.f/(1.f+expf(-s)));
  }
  __syncthreads();
  if (lane < 32){
    float s = b2[lane];
#pragma unroll
    for (int k=0;k<64;k++) s = fmaf(W2[lane*64 + k], y1[w][k], s);
    y2[w][lane] = s * (1.f/(1.f+expf(-s)));
  }
  __syncthreads();
  if (lane == 0){
    float s = bc[0];
#pragma unroll
    for (int k=0;k<32;k++) s = fmaf(Wc[k], y2[w][k], s);
    outp[b] = s;
  }
}

static inline size_t al256(size_t x){ return (x + 255) & ~(size_t)255; }

extern "C" void kernel_launch(void* const* d_in, const int* in_sizes, int n_in,
                              void* d_out, int out_size, void* d_ws, size_t ws_size,
                              hipStream_t stream)
{
  const float* x    = (const float*)d_in[0];
  const float* Wih0 = (const float*)d_in[1];
  const float* WihR = (const float*)d_in[2];
  const float* Whh  = (const float*)d_in[3];
  const float* bih  = (const float*)d_in[4];
  const float* bhh  = (const float*)d_in[5];
  const float* W1p  = (const float*)d_in[6];
  const float* b1p  = (const float*)d_in[7];
  const float* W2p  = (const float*)d_in[8];
  const float* b2p  = (const float*)d_in[9];
  const float* Wcp  = (const float*)d_in[10];
  const float* bcp  = (const float*)d_in[11];
  float* outp = (float*)d_out;
  (void)in_sizes; (void)n_in;

  auto need_basic = [](int nc) -> size_t {
    size_t c = B_ / nc;
    size_t s = 0;
    s += al256((size_t)2*T_*c*G_*sizeof(__half));   // gx
    s += al256((size_t)c*T_*DC_*sizeof(__half));    // buf
    s += al256((size_t)16*H_*G_*sizeof(__half));    // WF
    s += al256((size_t)2*c*H_*sizeof(float));       // hsum
    return s;
  };
  const size_t wih_bytes = al256((size_t)8*2*G_*DC_*sizeof(__half));  // 12.6 MB
  const bool full = (need_basic(1) + wih_bytes) <= ws_size;           // all-DMA path

  int NC = 1; bool fits = full;
  if (!full){
    const int ncs[5] = {1,2,4,8,16};
    for (int i=0;i<5;i++){ if (need_basic(ncs[i]) <= ws_size){ NC = ncs[i]; fits = true; break; } }
  }
  if (!fits){
    k_zero<<<(out_size + 255)/256, 256, 0, stream>>>(outp, out_size);
    return;
  }

  const size_t C = B_ / NC;
  char* p = (char*)d_ws;
  __half* gx   = (__half*)p;  p += al256((size_t)2*T_*C*G_*sizeof(__half));
  __half* buf  = (__half*)p;  p += al256((size_t)C*T_*DC_*sizeof(__half));
  __half* WF   = (__half*)p;  p += al256((size_t)16*H_*G_*sizeof(__half));
  float*  hsum = (float*)p;   p += al256((size_t)2*C*H_*sizeof(float));
  __half* Wh   = (__half*)p;  // only valid on full path

  k_pack_whh<<<dim3(8, 48, 16), 64, 0, stream>>>(Whh, WF);
  if (full)
    k_cvt_wih<<<(8*2*G_*64 + 255)/256, 256, 0, stream>>>(Wih0, WihR, Wh);

  for (int cc=0; cc<NC; cc++){
    const size_t b0c = (size_t)cc * C;
    k_cvt_x<<<(int)((C*T_*24 + 255)/256), 256, 0, stream>>>(x + b0c*T_*D0_, buf, (int)C);
    for (int l=0;l<L_;l++){
      const int Kpad = (l==0) ? 192 : DC_;
      if (full){
        k_gx_dma<<<dim3(C/128, G_/128, 2*T_), 256, 0, stream>>>(
            buf, Wh + (size_t)l*2*G_*DC_, bih + (size_t)l*2*G_, gx, (int)C, Kpad);
      } else {
        const float* Wi = (l==0) ? Wih0 : (WihR + (size_t)(l-1)*2*G_*DC_);
        const int KinW  = (l==0) ? D0_ : DC_;
        k_gx_mfma_f32w<<<dim3(C/128, G_/128, 2*T_), 256, 0, stream>>>(
            buf, Wi, bih + (size_t)l*2*G_, gx, (int)C, KinW, Kpad);
      }
      k_gru_rec<<<dim3(C/16, 2), 512, 0, stream>>>(
          gx, WF + (size_t)l*2*WFLD_, bhh + (size_t)l*2*G_, buf,
          hsum, (l==0) ? 1 : 0, (int)C);
    }
    k_head<<<dim3(C/4), 256, 0, stream>>>(hsum, W1p,b1p,W2p,b2p,Wcp,bcp,
                                          outp + b0c, (int)C);
  }
}